// Round 1
// 430.973 us; speedup vs baseline: 1.0183x; 1.0183x over previous
//
#include <hip/hip_runtime.h>

// Problem constants (fixed by setup_inputs)
#define TB 16
#define NHEADS 16
#define HD 32
#define WS 8
#define SS 4

typedef __attribute__((ext_vector_type(8))) __bf16 bf16x8;
typedef __attribute__((ext_vector_type(4))) float f32x4;

__device__ __forceinline__ unsigned short f2bf(float f) {
    unsigned u = __float_as_uint(f);
    u += 0x7fff + ((u >> 16) & 1);   // round-to-nearest-even
    return (unsigned short)(u >> 16);
}
__device__ __forceinline__ unsigned pk2(float a, float b) {
    return (unsigned)f2bf(a) | ((unsigned)f2bf(b) << 16);
}

// LDS layout (bytes), one (window,head) problem per 4-wave block:
//   [0,      5120)  Qs bf16 [64][40]  stride 80   -- overlaid by P after QK^T
//   [5120,  10240)  Ks bf16 [64][40]  stride 80   -- overlaid by P after QK^T
//   [0,      9216)  P  bf16 [64][72]  stride 144  (overlays Qs+Ks)
//   [10240, 14848)  Vt bf16 [32][72]  stride 144  (V transposed: [chan][token])
//   [14848, 15748)  Bs f32  [225]
#define OFF_Q 0
#define OFF_K 5120
#define OFF_P 0
#define OFF_V 10240
#define OFF_B 14848

__global__ __launch_bounds__(256, 8)
void swin_attn_mfma(const float* __restrict__ q,
                    const float* __restrict__ k,
                    const float* __restrict__ v,
                    const float* __restrict__ bias_table,
                    float* __restrict__ out)
{
    __shared__ __align__(16) char smem[15760];
    char* sQ = smem + OFF_Q;
    char* sK = smem + OFF_K;
    char* sP = smem + OFF_P;
    char* sV = smem + OFF_V;
    float* sB = (float*)(smem + OFF_B);

    const int blk  = blockIdx.x;            // 0..16383
    const int head = blk & (NHEADS - 1);
    const int win  = (blk >> 4) & 63;
    const int b    = blk >> 10;
    const int wh   = win >> 3;
    const int ww   = win & 7;

    const int tid  = threadIdx.x;           // 0..255
    const int wave = tid >> 6;              // 0..3  (tile row band mt)
    const int lane = tid & 63;
    const int quad = lane >> 4, lm = lane & 15;

    // ---- Phase 0: parallel staging. wave0=Q(scaled), wave1=K, wave2/3=V^T halves, wave3+=bias
    {
        const int ih = lane >> 3, iw = lane & 7;   // lane = token this lane stages
        const int gh = (wh * WS + ih + SS) & 63;
        const int gw = (ww * WS + iw + SS) & 63;
        const size_t rowbase = (((size_t)b * 64 + gh) * 64 + gw) * 512 + (size_t)head * HD;

        if (wave == 0) {
            const float scale = 0.17677669529663687f;  // 32^-0.5
            const float4* qrow = (const float4*)(q + rowbase);
            uint4* qd = (uint4*)(sQ + lane * 80);
            #pragma unroll
            for (int t = 0; t < 4; ++t) {
                float4 a = qrow[2 * t], c = qrow[2 * t + 1];
                uint4 w;
                w.x = pk2(a.x * scale, a.y * scale);
                w.y = pk2(a.z * scale, a.w * scale);
                w.z = pk2(c.x * scale, c.y * scale);
                w.w = pk2(c.z * scale, c.w * scale);
                qd[t] = w;
            }
        } else if (wave == 1) {
            const float4* krow = (const float4*)(k + rowbase);
            uint4* kd = (uint4*)(sK + lane * 80);
            #pragma unroll
            for (int t = 0; t < 4; ++t) {
                float4 a = krow[2 * t], c = krow[2 * t + 1];
                uint4 w;
                w.x = pk2(a.x, a.y);
                w.y = pk2(a.z, a.w);
                w.z = pk2(c.x, c.y);
                w.w = pk2(c.z, c.w);
                kd[t] = w;
            }
        } else {
            const int t0 = (wave == 2) ? 0 : 4;
            const float4* vrow = (const float4*)(v + rowbase);
            #pragma unroll
            for (int t = 0; t < 4; ++t) {
                float4 x = vrow[t0 + t];
                const int ch = 4 * (t0 + t);
                *(unsigned short*)(sV + (ch + 0) * 144 + lane * 2) = f2bf(x.x);
                *(unsigned short*)(sV + (ch + 1) * 144 + lane * 2) = f2bf(x.y);
                *(unsigned short*)(sV + (ch + 2) * 144 + lane * 2) = f2bf(x.z);
                *(unsigned short*)(sV + (ch + 3) * 144 + lane * 2) = f2bf(x.w);
            }
            if (wave == 3) {
                #pragma unroll
                for (int t = lane; t < 225; t += 64)
                    sB[t] = bias_table[t * NHEADS + head];
            }
        }
    }
    __syncthreads();

    // ---- Phase 1: S row-band = Q K^T. wave w computes tiles (mt=w, nt=0..3): 4 MFMAs ----
    bf16x8 qa = *(const bf16x8*)(sQ + (16 * wave + lm) * 80 + quad * 16);
    bf16x8 kb[4];
    #pragma unroll
    for (int nt = 0; nt < 4; ++nt)
        kb[nt] = *(const bf16x8*)(sK + (16 * nt + lm) * 80 + quad * 16);

    f32x4 S[4];
    #pragma unroll
    for (int nt = 0; nt < 4; ++nt) {
        f32x4 z = {0.f, 0.f, 0.f, 0.f};
        S[nt] = __builtin_amdgcn_mfma_f32_16x16x32_bf16(qa, kb[nt], z, 0, 0, 0);
    }
    // lane holds S[i][j]: i = 16*wave + 4*quad + r (r=reg), j = 16*nt + lm

    // ---- Phase 2: in-register softmax. Row sum = shfl_xor reduce across the 16 lm lanes ----
    const bool eh = (wh == 7), ew = (ww == 7);
    const int ihh = 2 * wave + (quad >> 1);   // i>>3, constant per lane
    const int jw  = lm & 7;                   // j&7, constant per lane
    float part[4] = {0.f, 0.f, 0.f, 0.f};
    #pragma unroll
    for (int nt = 0; nt < 4; ++nt) {
        const int jh = 2 * nt + (lm >> 3);
        const bool okh = !eh || ((ihh < 4) == (jh < 4));
        #pragma unroll
        for (int r = 0; r < 4; ++r) {
            const int iww = 4 * (quad & 1) + r;   // i&7
            float s = S[nt][r] + sB[(ihh - jh + 7) * 15 + (iww - jw + 7)];
            bool ok = okh && (!ew || ((iww < 4) == (jw < 4)));
            float e = ok ? __expf(s) : 0.f;       // masked: exp(s-100) ~ 0
            S[nt][r] = e;
            part[r] += e;
        }
    }
    #pragma unroll
    for (int m = 1; m <= 8; m <<= 1)
        #pragma unroll
        for (int r = 0; r < 4; ++r)
            part[r] += __shfl_xor(part[r], m, 64);
    float rl[4];
    #pragma unroll
    for (int r = 0; r < 4; ++r)
        rl[r] = 1.f / part[r];

    // ---- Phase 3: write normalized P (bf16, row-major) over Q/K region ----
    __syncthreads();   // all waves' Q/K fragment reads done before P overwrites
    #pragma unroll
    for (int nt = 0; nt < 4; ++nt)
        #pragma unroll
        for (int r = 0; r < 4; ++r)
            *(unsigned short*)(sP + (16 * wave + 4 * quad + r) * 144 + (16 * nt + lm) * 2)
                = f2bf(S[nt][r] * rl[r]);
    __syncthreads();

    // ---- Phase 4: O row-band = P V. wave w computes tiles (mt=w, nt=0..1): 4 MFMAs ----
    bf16x8 pa0 = *(const bf16x8*)(sP + (16 * wave + lm) * 144 + quad * 16);
    bf16x8 pa1 = *(const bf16x8*)(sP + (16 * wave + lm) * 144 + 64 + quad * 16);
    bf16x8 vb[2][2];
    #pragma unroll
    for (int nt = 0; nt < 2; ++nt)
        #pragma unroll
        for (int ks = 0; ks < 2; ++ks)
            vb[nt][ks] = *(const bf16x8*)(sV + (16 * nt + lm) * 144 + ks * 64 + quad * 16);

    f32x4 O[2];
    #pragma unroll
    for (int nt = 0; nt < 2; ++nt) {
        f32x4 z = {0.f, 0.f, 0.f, 0.f};
        z = __builtin_amdgcn_mfma_f32_16x16x32_bf16(pa0, vb[nt][0], z, 0, 0, 0);
        O[nt] = __builtin_amdgcn_mfma_f32_16x16x32_bf16(pa1, vb[nt][1], z, 0, 0, 0);
    }

    // ---- Phase 5: store O (row i = 16*wave+4*quad+r, col = 16*nt+lm) ----
    #pragma unroll
    for (int r = 0; r < 4; ++r) {
        const int i = 16 * wave + 4 * quad + r;
        const int ghh = (wh * WS + (i >> 3) + SS) & 63;
        const int gww = (ww * WS + (i & 7) + SS) & 63;
        float* rp = out + (((size_t)b * 64 + ghh) * 64 + gww) * 512 + (size_t)head * HD + lm;
        rp[0]  = O[0][r];
        rp[16] = O[1][r];
    }
}

extern "C" void kernel_launch(void* const* d_in, const int* in_sizes, int n_in,
                              void* d_out, int out_size, void* d_ws, size_t ws_size,
                              hipStream_t stream) {
    const float* q  = (const float*)d_in[0];
    const float* k  = (const float*)d_in[1];
    const float* v  = (const float*)d_in[2];
    const float* bt = (const float*)d_in[3];
    float* out = (float*)d_out;

    dim3 grid(TB * 64 * NHEADS);   // 16384 (window,head) problems, 4 waves each
    dim3 block(256);
    swin_attn_mfma<<<grid, block, 0, stream>>>(q, k, v, bt, out);
}